// Round 1
// baseline (5985.138 us; speedup 1.0000x reference)
//
#include <hip/hip_runtime.h>
#include <math.h>

// DNC forward, fp32. B=16 T=64 IN=256 H=512 M=256 W=64 R=4 IFACE=471.
// Workspace need: ~48.6 MB (asserted nowhere; harness ws is assumed >= 64MB).

#define BZ    16
#define TZ    64
#define HID   512
#define NCELL 256
#define CSZ   64
#define NRD   4
#define G4H   2048
#define IFC   471
#define DEL   1e-6f

__device__ __forceinline__ float sig_(float x) { return 1.f / (1.f + expf(-x)); }
__device__ __forceinline__ float splus_(float x) { return fmaxf(x, 0.f) + log1pf(expf(-fabsf(x))); }

__device__ __forceinline__ float blk_sum_(float v, volatile float* sred, int lane, int wid) {
#pragma unroll
  for (int off = 32; off; off >>= 1) v += __shfl_down(v, off);
  __syncthreads();
  if (lane == 0) sred[wid] = v;
  __syncthreads();
  return sred[0] + sred[1] + sred[2] + sred[3];
}
__device__ __forceinline__ float blk_max_(float v, volatile float* sred, int lane, int wid) {
#pragma unroll
  for (int off = 32; off; off >>= 1) v = fmaxf(v, __shfl_down(v, off));
  __syncthreads();
  if (lane == 0) sred[wid] = v;
  __syncthreads();
  return fmaxf(fmaxf(sred[0], sred[1]), fmaxf(sred[2], sred[3]));
}

// dst[c][r] = src[r][c] for c<kmax, r<rows. dst row stride = dst_stride.
__global__ __launch_bounds__(256) void k_transpose(const float* __restrict__ src,
                                                   float* __restrict__ dst,
                                                   int rows, int cols, int kmax, int dst_stride) {
  __shared__ float tile[32][33];
  int c0 = blockIdx.x * 32, r0 = blockIdx.y * 32;
  int tx = threadIdx.x, ty = threadIdx.y;
  for (int i = ty; i < 32; i += 8) {
    int r = r0 + i, c = c0 + tx;
    tile[i][tx] = (r < rows && c < cols) ? src[(size_t)r * cols + c] : 0.f;
  }
  __syncthreads();
  for (int i = ty; i < 32; i += 8) {
    int c = c0 + i, r = r0 + tx;
    if (c < kmax && r < rows) dst[(size_t)c * dst_stride + r] = tile[tx][i];
  }
}

// xpart[tb][jg] = sum_k x[b][t][k] * Wih0T[k][jg] + bih0[jg] + bhh0[jg]   (tb = t*16+b)
__global__ __launch_bounds__(256) void k_xpart(const float* __restrict__ x,
                                               const float* __restrict__ Wih0T,
                                               const float* __restrict__ bih0,
                                               const float* __restrict__ bhh0,
                                               float* __restrict__ xpart) {
  const int lane = threadIdx.x, ty = threadIdx.y;
  const int jg = blockIdx.x * 64 + lane;
  const int tb0 = blockIdx.y * 16;
  __shared__ float sx[16][256];
  const int tid = ty * 64 + lane;
  for (int idx = tid; idx < 16 * 256; idx += 256) {
    int row = idx >> 8, k = idx & 255;
    int tb = tb0 + row, tt = tb >> 4, bb = tb & 15;
    sx[row][k] = x[((size_t)bb * TZ + tt) * 256 + k];
  }
  __syncthreads();
  float acc[4] = {0.f, 0.f, 0.f, 0.f};
  for (int k = 0; k < 256; ++k) {
    float wv = Wih0T[(size_t)k * G4H + jg];
#pragma unroll
    for (int i = 0; i < 4; ++i) acc[i] = fmaf(wv, sx[ty * 4 + i][k], acc[i]);
  }
  float bias = bih0[jg] + bhh0[jg];
#pragma unroll
  for (int i = 0; i < 4; ++i)
    xpart[(size_t)(tb0 + ty * 4 + i) * G4H + jg] = acc[i] + bias;
}

// LSTM cell 0: gates = xpart[t] + h0_old @ Whh0^T ; writes h0[new], c0.
// grid (8,16) block (64,4): j = bx*64+tx, b = by, K split over ty (4x128).
__global__ __launch_bounds__(256) void k_lstm0(const float* __restrict__ xpart,
                                               const float* __restrict__ WhhT,
                                               float* __restrict__ h0,
                                               float* __restrict__ c0, int t) {
  const int jl = threadIdx.x, ks = threadIdx.y;
  const int j = blockIdx.x * 64 + jl;
  const int b = blockIdx.y;
  const int po = t & 1, pn = po ^ 1;
  __shared__ float sh[512];
  __shared__ float sred[4][4][64];
  const float* h0o = h0 + ((size_t)po * BZ + b) * HID;
  const int tid = ks * 64 + jl;
  for (int k = tid; k < 512; k += 256) sh[k] = h0o[k];
  __syncthreads();
  float a0 = 0.f, a1 = 0.f, a2 = 0.f, a3 = 0.f;
  const int kb = ks * 128;
#pragma unroll 4
  for (int k = kb; k < kb + 128; ++k) {
    const float hk = sh[k];
    const float* wr = WhhT + (size_t)k * G4H + j;
    a0 = fmaf(hk, wr[0], a0);
    a1 = fmaf(hk, wr[512], a1);
    a2 = fmaf(hk, wr[1024], a2);
    a3 = fmaf(hk, wr[1536], a3);
  }
  sred[ks][0][jl] = a0; sred[ks][1][jl] = a1; sred[ks][2][jl] = a2; sred[ks][3][jl] = a3;
  __syncthreads();
  if (ks == 0) {
    const float* xp = xpart + ((size_t)t * BZ + b) * G4H;
    float gi = sred[0][0][jl] + sred[1][0][jl] + sred[2][0][jl] + sred[3][0][jl] + xp[j];
    float gf = sred[0][1][jl] + sred[1][1][jl] + sred[2][1][jl] + sred[3][1][jl] + xp[512 + j];
    float gg = sred[0][2][jl] + sred[1][2][jl] + sred[2][2][jl] + sred[3][2][jl] + xp[1024 + j];
    float go = sred[0][3][jl] + sred[1][3][jl] + sred[2][3][jl] + sred[3][3][jl] + xp[1536 + j];
    gi = sig_(gi); gf = sig_(gf); go = sig_(go); gg = tanhf(gg);
    float* cp = c0 + b * HID + j;
    float cc = gf * (*cp) + gi * gg;
    *cp = cc;
    h0[((size_t)pn * BZ + b) * HID + j] = go * tanhf(cc);
  }
}

// LSTM cell 1: gates = h0_new @ Wih1^T + h1_old @ Whh1^T + bih1 + bhh1
__global__ __launch_bounds__(256) void k_lstm1(const float* __restrict__ WihT,
                                               const float* __restrict__ WhhT,
                                               const float* __restrict__ bih,
                                               const float* __restrict__ bhh,
                                               const float* __restrict__ h0,
                                               float* __restrict__ h1,
                                               float* __restrict__ c1, int t) {
  const int jl = threadIdx.x, ks = threadIdx.y;
  const int j = blockIdx.x * 64 + jl;
  const int b = blockIdx.y;
  const int po = t & 1, pn = po ^ 1;
  __shared__ float sh0[512], sh1[512];
  __shared__ float sred[4][4][64];
  const float* h0n = h0 + ((size_t)pn * BZ + b) * HID;
  const float* h1o = h1 + ((size_t)po * BZ + b) * HID;
  const int tid = ks * 64 + jl;
  for (int k = tid; k < 512; k += 256) { sh0[k] = h0n[k]; sh1[k] = h1o[k]; }
  __syncthreads();
  float a0 = 0.f, a1 = 0.f, a2 = 0.f, a3 = 0.f;
  const int kb = ks * 128;
#pragma unroll 2
  for (int k = kb; k < kb + 128; ++k) {
    const float x0 = sh0[k], x1 = sh1[k];
    const float* wi = WihT + (size_t)k * G4H + j;
    const float* wh = WhhT + (size_t)k * G4H + j;
    a0 = fmaf(x0, wi[0], fmaf(x1, wh[0], a0));
    a1 = fmaf(x0, wi[512], fmaf(x1, wh[512], a1));
    a2 = fmaf(x0, wi[1024], fmaf(x1, wh[1024], a2));
    a3 = fmaf(x0, wi[1536], fmaf(x1, wh[1536], a3));
  }
  sred[ks][0][jl] = a0; sred[ks][1][jl] = a1; sred[ks][2][jl] = a2; sred[ks][3][jl] = a3;
  __syncthreads();
  if (ks == 0) {
    float gi = sred[0][0][jl] + sred[1][0][jl] + sred[2][0][jl] + sred[3][0][jl] + bih[j] + bhh[j];
    float gf = sred[0][1][jl] + sred[1][1][jl] + sred[2][1][jl] + sred[3][1][jl] + bih[512 + j] + bhh[512 + j];
    float gg = sred[0][2][jl] + sred[1][2][jl] + sred[2][2][jl] + sred[3][2][jl] + bih[1024 + j] + bhh[1024 + j];
    float go = sred[0][3][jl] + sred[1][3][jl] + sred[2][3][jl] + sred[3][3][jl] + bih[1536 + j] + bhh[1536 + j];
    gi = sig_(gi); gf = sig_(gf); go = sig_(go); gg = tanhf(gg);
    float* cp = c1 + b * HID + j;
    float cc = gf * (*cp) + gi * gg;
    *cp = cc;
    h1[((size_t)pn * BZ + b) * HID + j] = go * tanhf(cc);
  }
}

// out = h1@Wout^T + bout (stored for final GEMM); xi = h1@Wif^T + bif (raw).
// grid (16,16): u = bx*64+tx in [0,1024): u<512 -> out, else xi col u-512.
__global__ __launch_bounds__(256) void k_outxi(const float* __restrict__ WoutT,
                                               const float* __restrict__ WifT,
                                               const float* __restrict__ bout,
                                               const float* __restrict__ bif,
                                               const float* __restrict__ h1,
                                               float* __restrict__ out_all,
                                               float* __restrict__ xig, int t) {
  const int jl = threadIdx.x, ks = threadIdx.y;
  const int u = blockIdx.x * 64 + jl;
  const int b = blockIdx.y;
  const int pn = (t & 1) ^ 1;
  __shared__ float sh[512];
  __shared__ float sred[4][64];
  const float* h1p = h1 + ((size_t)pn * BZ + b) * HID;
  const int tid = ks * 64 + jl;
  for (int k = tid; k < 512; k += 256) sh[k] = h1p[k];
  __syncthreads();
  const float* base = (u < 512) ? (WoutT + u) : (WifT + (u - 512));
  float a = 0.f;
  const int kb = ks * 128;
#pragma unroll 4
  for (int k = kb; k < kb + 128; ++k) a = fmaf(sh[k], base[(size_t)k * 512], a);
  sred[ks][jl] = a;
  __syncthreads();
  if (ks == 0) {
    float s = sred[0][jl] + sred[1][jl] + sred[2][jl] + sred[3][jl];
    if (u < 512) out_all[((size_t)t * BZ + b) * HID + u] = s + bout[u];
    else {
      int i = u - 512;
      if (i < IFC) xig[b * 512 + i] = s + bif[i];
    }
  }
}

// Controller: parse xi, usage update, write-content-weights, allocation (rank-based
// stable argsort + exclusive cumprod scan), write weighting ww, precedence.
// One 256-thread block per batch.
__global__ __launch_bounds__(256) void k_ctrl(const float* __restrict__ xig,
                                              const float* __restrict__ membuf,
                                              const float* __restrict__ rwbuf,
                                              float* __restrict__ wwg,
                                              float* __restrict__ usageg,
                                              float* __restrict__ precbuf,
                                              float* __restrict__ pxi, int t) {
  const int b = blockIdx.x;
  const int tid = threadIdx.x;
  const int lane = tid & 63, wid = tid >> 6;
  const int po = t & 1, pn = po ^ 1;
  __shared__ float sxi[IFC];
  __shared__ float srkn[256];
  __shared__ float swkn[64];
  __shared__ float sscal[32];
  __shared__ float su[256];
  __shared__ float ssort[256];
  __shared__ float sscan[256];
  __shared__ float sred[8];

  for (int i = tid; i < IFC; i += 256) sxi[i] = xig[b * 512 + i];
  __syncthreads();

  // read keys (tanh, per-head L2 normalization with +DELTA)
  float rv = tanhf(sxi[tid]);
  {
    float ss2 = rv * rv;
#pragma unroll
    for (int off = 32; off; off >>= 1) ss2 += __shfl_down(ss2, off);
    if (lane == 0) sred[wid] = 1.f / (sqrtf(ss2) + DEL);
  }
  float wkv = 0.f;
  if (tid < 64) {
    wkv = tanhf(sxi[260 + tid]);
    float s2 = wkv * wkv;
#pragma unroll
    for (int off = 32; off; off >>= 1) s2 += __shfl_down(s2, off);
    if (tid == 0) sred[4] = 1.f / (sqrtf(s2) + DEL);
  }
  __syncthreads();
  srkn[tid] = rv * sred[wid];
  if (tid < 64) swkn[tid] = wkv * sred[4];
  if (tid < 4) sscal[tid] = splus_(sxi[256 + tid]);                  // rs
  if (tid == 4) sscal[4] = splus_(sxi[324]);                         // ws
  if (tid >= 8 && tid < 12) sscal[tid] = sig_(sxi[453 + (tid - 8)]); // fg
  if (tid == 12) sscal[12] = sig_(sxi[457]);                         // ag
  if (tid == 13) sscal[13] = sig_(sxi[458]);                         // wg
  if (tid >= 16 && tid < 20) {                                       // rm softmax rows
    int r = tid - 16;
    float a = sxi[459 + r * 3], b2 = sxi[460 + r * 3], c2 = sxi[461 + r * 3];
    float mx3 = fmaxf(a, fmaxf(b2, c2));
    float ea = expf(a - mx3), eb = expf(b2 - mx3), ec = expf(c2 - mx3);
    float iv = 1.f / (ea + eb + ec);
    sscal[20 + r * 3 + 0] = ea * iv;
    sscal[20 + r * 3 + 1] = eb * iv;
    sscal[20 + r * 3 + 2] = ec * iv;
  }
  __syncthreads();

  // usage update (uses previous ww and previous rw)
  const float wwo = wwg[b * NCELL + tid];
  float uo = usageg[b * NCELL + tid];
  float u1 = uo + (1.f - uo) * wwo;
  float psi = 1.f;
#pragma unroll
  for (int r = 0; r < 4; ++r)
    psi *= 1.f - sscal[8 + r] * rwbuf[(((size_t)po * BZ + b) * NRD + r) * NCELL + tid];
  float un = u1 * psi;
  usageg[b * NCELL + tid] = un;

  // write content weights vs OLD memory
  const float* mrow = membuf + (((size_t)po * BZ + b) * NCELL + tid) * CSZ;
  float dot = 0.f, nn2 = 0.f;
#pragma unroll 8
  for (int w = 0; w < CSZ; ++w) {
    float mv = mrow[w];
    dot = fmaf(mv, swkn[w], dot);
    nn2 = fmaf(mv, mv, nn2);
  }
  float simv = sscal[4] * dot / (sqrtf(nn2) + DEL);
  float mx = blk_max_(simv, sred, lane, wid);
  float ee = expf(simv - mx);
  float sm = blk_sum_(ee, sred, lane, wid);
  float wcw = ee / sm;

  // allocation: rank == stable ascending argsort position
  float uadj = DEL + (1.f - DEL) * un;
  su[tid] = uadj;
  __syncthreads();
  int rank = 0;
  for (int j = 0; j < 256; ++j) {
    float uj = su[j];
    rank += (uj < uadj || (uj == uadj && j < tid)) ? 1 : 0;
  }
  ssort[rank] = uadj;
  __syncthreads();
  float inc = ssort[tid];
#pragma unroll
  for (int off = 1; off < 64; off <<= 1) {
    float pp = __shfl_up(inc, off);
    if (lane >= off) inc *= pp;
  }
  __syncthreads();
  if (lane == 63) sred[wid] = inc;
  __syncthreads();
  float pref = 1.f;
  for (int w2 = 0; w2 < wid; ++w2) pref *= sred[w2];
  float excl = __shfl_up(inc, 1);
  if (lane == 0) excl = 1.f;
  excl *= pref;
  sscan[tid] = excl;
  __syncthreads();
  float alo = (1.f - uadj) * sscan[rank];

  // write weighting + precedence
  float ag = sscal[12], wg = sscal[13];
  float wwn = wg * (ag * alo + (1.f - ag) * wcw);
  wwg[b * NCELL + tid] = wwn;
  float wsum = blk_sum_(wwn, sred, lane, wid);
  float pold = precbuf[((size_t)po * BZ + b) * NCELL + tid];
  precbuf[((size_t)pn * BZ + b) * NCELL + tid] = (1.f - wsum) * pold + wwn;

  // parsed interface values for later kernels
  pxi[b * 512 + tid] = srkn[tid];
  if (tid < 4) pxi[b * 512 + 256 + tid] = sscal[tid];
  if (tid < 64) {
    pxi[b * 512 + 260 + tid] = sig_(sxi[325 + tid]);   // erase vec
    pxi[b * 512 + 324 + tid] = tanhf(sxi[389 + tid]);  // write vec
  }
  if (tid < 12) pxi[b * 512 + 388 + tid] = sscal[20 + tid];
}

// Link/linkT update (+diag mask), memory erase/write, read-content sim, fwd, bwd.
// grid (256, 16, 2): x=row, y=batch, z=segment (0: link rows + mem + fwd + sim, 1: linkT rows + bwd)
__global__ __launch_bounds__(256) void k_linkmem(const float* __restrict__ wwg,
                                                 const float* __restrict__ precbuf,
                                                 const float* __restrict__ rwbuf,
                                                 const float* __restrict__ pxi,
                                                 float* __restrict__ linkbuf,
                                                 float* __restrict__ linkTbuf,
                                                 float* __restrict__ membuf,
                                                 float* __restrict__ simbuf,
                                                 float* __restrict__ fwdbuf,
                                                 float* __restrict__ bwdbuf, int t) {
  const int m = blockIdx.x;
  const int b = blockIdx.y;
  const int tid = threadIdx.x;
  const int lane = tid & 63, wid = tid >> 6;
  const int po = t & 1, pn = po ^ 1;
  __shared__ float spart[4][4];
  const float wrow = wwg[b * NCELL + m];
  const float prow = precbuf[((size_t)po * BZ + b) * NCELL + m];
  const float wcol = wwg[b * NCELL + tid];
  const float pcol = precbuf[((size_t)po * BZ + b) * NCELL + tid];
  const float rr0 = rwbuf[(((size_t)po * BZ + b) * NRD + 0) * NCELL + tid];
  const float rr1 = rwbuf[(((size_t)po * BZ + b) * NRD + 1) * NCELL + tid];
  const float rr2 = rwbuf[(((size_t)po * BZ + b) * NRD + 2) * NCELL + tid];
  const float rr3 = rwbuf[(((size_t)po * BZ + b) * NRD + 3) * NCELL + tid];
  const size_t obase = (((size_t)po * BZ + b) * NCELL + m) * NCELL;
  const size_t nbase = (((size_t)pn * BZ + b) * NCELL + m) * NCELL;
  float p0, p1, p2, p3;
  if (blockIdx.z == 0) {
    float lo = linkbuf[obase + tid];
    float lv = (1.f - wrow - wcol) * lo + wrow * pcol;
    if (tid == m) lv = 0.f;
    linkbuf[nbase + tid] = lv;
    p0 = lv * rr0; p1 = lv * rr1; p2 = lv * rr2; p3 = lv * rr3;
    if (tid < 64) {  // memory erase/write + read-content sim for row m (wave 0)
      float evw = pxi[b * 512 + 260 + tid];
      float wvw = pxi[b * 512 + 324 + tid];
      size_t mi = (((size_t)po * BZ + b) * NCELL + m) * CSZ + tid;
      size_t mo = (((size_t)pn * BZ + b) * NCELL + m) * CSZ + tid;
      float mold = membuf[mi];
      float mnew = mold * (1.f - wrow * evw) + wrow * wvw;
      membuf[mo] = mnew;
      float n2 = mnew * mnew;
      float d0 = mnew * pxi[b * 512 + 0 * 64 + tid];
      float d1 = mnew * pxi[b * 512 + 1 * 64 + tid];
      float d2 = mnew * pxi[b * 512 + 2 * 64 + tid];
      float d3 = mnew * pxi[b * 512 + 3 * 64 + tid];
#pragma unroll
      for (int off = 32; off; off >>= 1) {
        n2 += __shfl_down(n2, off);
        d0 += __shfl_down(d0, off);
        d1 += __shfl_down(d1, off);
        d2 += __shfl_down(d2, off);
        d3 += __shfl_down(d3, off);
      }
      if (tid == 0) {
        float invn = 1.f / (sqrtf(n2) + DEL);
        simbuf[(b * NRD + 0) * NCELL + m] = pxi[b * 512 + 256 + 0] * d0 * invn;
        simbuf[(b * NRD + 1) * NCELL + m] = pxi[b * 512 + 256 + 1] * d1 * invn;
        simbuf[(b * NRD + 2) * NCELL + m] = pxi[b * 512 + 256 + 2] * d2 * invn;
        simbuf[(b * NRD + 3) * NCELL + m] = pxi[b * 512 + 256 + 3] * d3 * invn;
      }
    }
  } else {
    float lto = linkTbuf[obase + tid];
    float lt = (1.f - wcol - wrow) * lto + wcol * prow;  // linkT_new[n=m][m'=tid]
    if (tid == m) lt = 0.f;
    linkTbuf[nbase + tid] = lt;
    p0 = lt * rr0; p1 = lt * rr1; p2 = lt * rr2; p3 = lt * rr3;
  }
#pragma unroll
  for (int off = 32; off; off >>= 1) {
    p0 += __shfl_down(p0, off);
    p1 += __shfl_down(p1, off);
    p2 += __shfl_down(p2, off);
    p3 += __shfl_down(p3, off);
  }
  if (lane == 0) { spart[wid][0] = p0; spart[wid][1] = p1; spart[wid][2] = p2; spart[wid][3] = p3; }
  __syncthreads();
  if (tid < 4) {
    float s = spart[0][tid] + spart[1][tid] + spart[2][tid] + spart[3][tid];
    float* dst = (blockIdx.z == 0) ? fwdbuf : bwdbuf;
    dst[(b * NRD + tid) * NCELL + m] = s;
  }
}

// Read: softmax(sim) per head, rw = rm0*bwd + rm1*fwd + rm2*cw, read_vecs = rw @ mem_new.
__global__ __launch_bounds__(256) void k_read(const float* __restrict__ simbuf,
                                              const float* __restrict__ fwdbuf,
                                              const float* __restrict__ bwdbuf,
                                              const float* __restrict__ pxi,
                                              const float* __restrict__ membuf,
                                              float* __restrict__ rwbuf,
                                              float* __restrict__ rv_all, int t) {
  const int b = blockIdx.x;
  const int tid = threadIdx.x;
  const int lane = tid & 63, wid = tid >> 6;
  const int po = t & 1, pn = po ^ 1;
  (void)po;
  __shared__ float srw[4][256];
  __shared__ float sred[8];
#pragma unroll
  for (int r = 0; r < 4; ++r) {
    float v = simbuf[(b * NRD + r) * NCELL + tid];
    float mx = blk_max_(v, sred, lane, wid);
    float e = expf(v - mx);
    float s = blk_sum_(e, sred, lane, wid);
    float cw = e / s;
    float rm0 = pxi[b * 512 + 388 + r * 3 + 0];
    float rm1 = pxi[b * 512 + 388 + r * 3 + 1];
    float rm2 = pxi[b * 512 + 388 + r * 3 + 2];
    float rwn = rm0 * bwdbuf[(b * NRD + r) * NCELL + tid] +
                rm1 * fwdbuf[(b * NRD + r) * NCELL + tid] + rm2 * cw;
    srw[r][tid] = rwn;
    rwbuf[(((size_t)pn * BZ + b) * NRD + r) * NCELL + tid] = rwn;
  }
  __syncthreads();
  // read vectors: wave r computes 64 components over m
  const float* mbase = membuf + (((size_t)pn * BZ + b) * NCELL) * CSZ;
  float acc = 0.f;
  for (int mm = 0; mm < 256; ++mm)
    acc = fmaf(srw[wid][mm], mbase[(size_t)mm * CSZ + lane], acc);
  rv_all[((size_t)t * BZ + b) * 256 + wid * 64 + lane] = acc;
}

// Final output GEMM over all (t,b): y = [out, read_vecs] @ Wmem^T + bmem, to (B,T,IN) layout.
__global__ __launch_bounds__(256) void k_y(const float* __restrict__ out_all,
                                           const float* __restrict__ rv_all,
                                           const float* __restrict__ WmemT,
                                           const float* __restrict__ bmem,
                                           float* __restrict__ y) {
  const int lane = threadIdx.x, ty = threadIdx.y;
  const int o = blockIdx.x * 64 + lane;
  const int tb0 = blockIdx.y * 16;
  __shared__ float sin_[16][768];
  const int tid = ty * 64 + lane;
  for (int idx = tid; idx < 16 * 768; idx += 256) {
    int row = idx / 768, k = idx % 768;
    int tb = tb0 + row;
    sin_[row][k] = (k < 512) ? out_all[(size_t)tb * HID + k]
                             : rv_all[(size_t)tb * 256 + (k - 512)];
  }
  __syncthreads();
  float acc[4] = {0.f, 0.f, 0.f, 0.f};
  for (int k = 0; k < 768; ++k) {
    float wv = WmemT[(size_t)k * 256 + o];
#pragma unroll
    for (int i = 0; i < 4; ++i) acc[i] = fmaf(wv, sin_[ty * 4 + i][k], acc[i]);
  }
  float bo = bmem[o];
#pragma unroll
  for (int i = 0; i < 4; ++i) {
    int tb = tb0 + ty * 4 + i;
    int tt = tb >> 4, bb = tb & 15;
    y[((size_t)bb * TZ + tt) * 256 + o] = acc[i] + bo;
  }
}

extern "C" void kernel_launch(void* const* d_in, const int* in_sizes, int n_in,
                              void* d_out, int out_size, void* d_ws, size_t ws_size,
                              hipStream_t stream) {
  (void)in_sizes; (void)n_in; (void)out_size; (void)ws_size;
  const float* x    = (const float*)d_in[0];
  const float* Wih0 = (const float*)d_in[1];
  const float* bih0 = (const float*)d_in[2];
  const float* Whh0 = (const float*)d_in[3];
  const float* bhh0 = (const float*)d_in[4];
  const float* Wih1 = (const float*)d_in[5];
  const float* bih1 = (const float*)d_in[6];
  const float* Whh1 = (const float*)d_in[7];
  const float* bhh1 = (const float*)d_in[8];
  const float* Wout = (const float*)d_in[9];
  const float* bout = (const float*)d_in[10];
  const float* Wif  = (const float*)d_in[11];
  const float* bif  = (const float*)d_in[12];
  const float* Wmem = (const float*)d_in[13];
  const float* bmem = (const float*)d_in[14];
  float* y = (float*)d_out;

  float* p = (float*)d_ws;
  auto take = [&](size_t n) { float* q = p; p += n; return q; };
  float* Wih0T  = take((size_t)256 * 2048);
  float* Whh0T  = take((size_t)512 * 2048);
  float* Wih1T  = take((size_t)512 * 2048);
  float* Whh1T  = take((size_t)512 * 2048);
  float* WoutT  = take((size_t)512 * 512);
  float* WifT   = take((size_t)512 * 512);   // padded cols >=471 unused
  float* WmemT  = take((size_t)768 * 256);
  float* xpart  = take((size_t)TZ * BZ * G4H);
  float* out_all = take((size_t)TZ * BZ * HID);
  float* rv_all  = take((size_t)TZ * BZ * 256);
  float* xibuf   = take((size_t)BZ * 512);
  float* pxi     = take((size_t)BZ * 512);
  float* simbuf  = take((size_t)BZ * NRD * NCELL);
  float* fwdbuf  = take((size_t)BZ * NRD * NCELL);
  float* bwdbuf  = take((size_t)BZ * NRD * NCELL);
  float* zstart  = p;
  float* h0      = take((size_t)2 * BZ * HID);
  float* c0      = take((size_t)BZ * HID);
  float* h1      = take((size_t)2 * BZ * HID);
  float* c1      = take((size_t)BZ * HID);
  float* membuf  = take((size_t)2 * BZ * NCELL * CSZ);
  float* linkbuf = take((size_t)2 * BZ * NCELL * NCELL);
  float* linkTbuf = take((size_t)2 * BZ * NCELL * NCELL);
  float* precbuf = take((size_t)2 * BZ * NCELL);
  float* rwbuf   = take((size_t)2 * BZ * NRD * NCELL);
  float* wwg     = take((size_t)BZ * NCELL);
  float* usageg  = take((size_t)BZ * NCELL);
  size_t zbytes = (size_t)((char*)p - (char*)zstart);

  hipMemsetAsync(zstart, 0, zbytes, stream);

  dim3 tb32(32, 8);
  hipLaunchKernelGGL(k_transpose, dim3(8, 64), tb32, 0, stream, Wih0, Wih0T, 2048, 512, 256, 2048);
  hipLaunchKernelGGL(k_transpose, dim3(16, 64), tb32, 0, stream, Whh0, Whh0T, 2048, 512, 512, 2048);
  hipLaunchKernelGGL(k_transpose, dim3(16, 64), tb32, 0, stream, Wih1, Wih1T, 2048, 512, 512, 2048);
  hipLaunchKernelGGL(k_transpose, dim3(16, 64), tb32, 0, stream, Whh1, Whh1T, 2048, 512, 512, 2048);
  hipLaunchKernelGGL(k_transpose, dim3(16, 16), tb32, 0, stream, Wout, WoutT, 512, 512, 512, 512);
  hipLaunchKernelGGL(k_transpose, dim3(16, 15), tb32, 0, stream, Wif, WifT, 471, 512, 512, 512);
  hipLaunchKernelGGL(k_transpose, dim3(24, 8), tb32, 0, stream, Wmem, WmemT, 256, 768, 768, 256);

  hipLaunchKernelGGL(k_xpart, dim3(32, 64), dim3(64, 4), 0, stream, x, Wih0T, bih0, bhh0, xpart);

  for (int t = 0; t < TZ; ++t) {
    hipLaunchKernelGGL(k_lstm0, dim3(8, 16), dim3(64, 4), 0, stream, xpart, Whh0T, h0, c0, t);
    hipLaunchKernelGGL(k_lstm1, dim3(8, 16), dim3(64, 4), 0, stream, Wih1T, Whh1T, bih1, bhh1, h0, h1, c1, t);
    hipLaunchKernelGGL(k_outxi, dim3(16, 16), dim3(64, 4), 0, stream, WoutT, WifT, bout, bif, h1, out_all, xibuf, t);
    hipLaunchKernelGGL(k_ctrl, dim3(16), dim3(256), 0, stream, xibuf, membuf, rwbuf, wwg, usageg, precbuf, pxi, t);
    hipLaunchKernelGGL(k_linkmem, dim3(256, 16, 2), dim3(256), 0, stream, wwg, precbuf, rwbuf, pxi,
                       linkbuf, linkTbuf, membuf, simbuf, fwdbuf, bwdbuf, t);
    hipLaunchKernelGGL(k_read, dim3(16), dim3(256), 0, stream, simbuf, fwdbuf, bwdbuf, pxi, membuf, rwbuf, rv_all, t);
  }

  hipLaunchKernelGGL(k_y, dim3(4, 64), dim3(64, 4), 0, stream, out_all, rv_all, WmemT, bmem, y);
}